// Round 2
// baseline (19997.792 us; speedup 1.0000x reference)
//
#include <hip/hip_runtime.h>
#include <hip/hip_bf16.h>
#include <math.h>

// ---- problem constants ----
constexpr int NN   = 131072;   // total nodes (B*NPG)
constexpr int NE   = 262144;   // edges
constexpr int BG   = 256;      // graphs
constexpr int CH   = 32;       // graphs per chunk
constexpr int NCHUNK = BG/CH;  // 8
constexpr int NCN  = CH*512;   // nodes per chunk = 16384

__device__ inline float sigm(float x){ return 1.f/(1.f+__expf(-x)); }

__global__ void k_zero(int* __restrict__ p, int n){
  int i = blockIdx.x*256 + threadIdx.x;
  if (i < n) p[i] = 0;
}

// ---------------- node encoder ----------------
__global__ void k_node_enc(const int* __restrict__ x, const float* __restrict__ emb,
                           float* __restrict__ h0){
  int n = blockIdx.x*256 + threadIdx.x;
  if (n >= NN) return;
  int nt = x[2*n], ninv = x[2*n+1];
  float4 v; v.x = emb[nt*3+0]; v.y = emb[nt*3+1]; v.z = emb[nt*3+2]; v.w = (float)ninv;
  reinterpret_cast<float4*>(h0)[n] = v;
}

// ---------------- CSR build (by dst) ----------------
__global__ void k_count(const int* __restrict__ ei, int* __restrict__ deg){
  int e = blockIdx.x*256 + threadIdx.x;
  if (e >= NE) return;
  atomicAdd(&deg[ei[NE + e]], 1);
}
__global__ void k_blocksum(const int* __restrict__ deg, int* __restrict__ bsum){
  __shared__ int sd[256];
  int t = threadIdx.x;
  const int* p = deg + blockIdx.x*1024;
  int s = p[t*4] + p[t*4+1] + p[t*4+2] + p[t*4+3];
  sd[t]=s; __syncthreads();
  for (int d=128; d>0; d>>=1){ if (t<d) sd[t]+=sd[t+d]; __syncthreads(); }
  if (!t) bsum[blockIdx.x] = sd[0];
}
__global__ void k_scanbsum(const int* __restrict__ bsum, int* __restrict__ boff, int* __restrict__ offN){
  __shared__ int s[128];
  int t = threadIdx.x;           // 128 threads
  int mine = bsum[t];
  s[t]=mine; __syncthreads();
  for (int d=1; d<128; d<<=1){ int v = (t>=d)? s[t-d]:0; __syncthreads(); s[t]+=v; __syncthreads(); }
  boff[t] = s[t]-mine;
  if (t==127) offN[0] = s[127];
}
__global__ void k_scanchunk(const int* __restrict__ deg, const int* __restrict__ boff, int* __restrict__ offs){
  __shared__ int ts[256];
  int t = threadIdx.x, b = blockIdx.x;
  const int* p = deg + b*1024;
  int v0=p[t*4],v1=p[t*4+1],v2=p[t*4+2],v3=p[t*4+3];
  int mysum=v0+v1+v2+v3;
  ts[t]=mysum; __syncthreads();
  for (int d=1; d<256; d<<=1){ int v=(t>=d)?ts[t-d]:0; __syncthreads(); ts[t]+=v; __syncthreads(); }
  int ex = ts[t]-mysum + boff[b];
  int* o = offs + b*1024 + t*4;
  o[0]=ex; o[1]=ex+v0; o[2]=ex+v0+v1; o[3]=ex+v0+v1+v2;
}
__global__ void k_fill(const int* __restrict__ ei, const int* __restrict__ offs,
                       int* __restrict__ cur, int* __restrict__ esrc){
  int e = blockIdx.x*256 + threadIdx.x;
  if (e >= NE) return;
  int dst = ei[NE+e];
  int pos = offs[dst] + atomicAdd(&cur[dst],1);
  esrc[pos] = ei[e];
}

// ---------------- softmax aggregation, 4-channel (conv1) ----------------
__global__ void k_aggr4(const float* __restrict__ h, const int* __restrict__ offs,
                        const int* __restrict__ esrc, const float* __restrict__ tptr,
                        float* __restrict__ ag){
  int n = blockIdx.x*256 + threadIdx.x;
  if (n >= NN) return;
  int s = offs[n], e = offs[n+1];
  float4 z = {0,0,0,0};
  if (s == e){ reinterpret_cast<float4*>(ag)[n] = z; return; }
  float t = *tptr;
  float4 m = {-3e38f,-3e38f,-3e38f,-3e38f};
  for (int i=s;i<e;++i){
    float4 v = reinterpret_cast<const float4*>(h)[esrc[i]];
    m.x=fmaxf(m.x,v.x*t); m.y=fmaxf(m.y,v.y*t); m.z=fmaxf(m.z,v.z*t); m.w=fmaxf(m.w,v.w*t);
  }
  float4 num=z, den=z;
  for (int i=s;i<e;++i){
    float4 v = reinterpret_cast<const float4*>(h)[esrc[i]];
    float ex;
    ex=__expf(v.x*t-m.x); num.x+=v.x*ex; den.x+=ex;
    ex=__expf(v.y*t-m.y); num.y+=v.y*ex; den.y+=ex;
    ex=__expf(v.z*t-m.z); num.z+=v.z*ex; den.z+=ex;
    ex=__expf(v.w*t-m.w); num.w+=v.w*ex; den.w+=ex;
  }
  float4 r = {num.x/den.x, num.y/den.y, num.z/den.z, num.w/den.w};
  reinterpret_cast<float4*>(ag)[n] = r;
}

// ---------------- softmax aggregation, 256-channel, chunked ----------------
__global__ __launch_bounds__(256) void k_aggr256(const float* __restrict__ hloc, const int* __restrict__ offs,
                          const int* __restrict__ esrc, const float* __restrict__ tptr,
                          float* __restrict__ ag, int base){
  int n = base + blockIdx.x, c = threadIdx.x;
  int s = offs[n], e = offs[n+1];
  if (s == e){ ag[(size_t)blockIdx.x*256+c] = 0.f; return; }
  float t = *tptr;
  float m = -3e38f;
  for (int i=s;i<e;++i) m = fmaxf(m, hloc[(size_t)(esrc[i]-base)*256 + c]*t);
  float num=0.f, den=0.f;
  for (int i=s;i<e;++i){
    float v = hloc[(size_t)(esrc[i]-base)*256 + c];
    float ex = __expf(v*t - m);
    num += v*ex; den += ex;
  }
  ag[(size_t)blockIdx.x*256+c] = num/den;
}

// ---------------- conv1 linear (K=4, fused), chunked ----------------
__global__ __launch_bounds__(256) void k_conv1_lin(const float* __restrict__ ag, const float* __restrict__ h0,
                            const float* __restrict__ lW, const float* __restrict__ lb,
                            const float* __restrict__ rW, float* __restrict__ out, int base){
  int n = base + blockIdx.x, c = threadIdx.x;
  float4 a  = reinterpret_cast<const float4*>(ag)[n];
  float4 xv = reinterpret_cast<const float4*>(h0)[n];
  float acc = lb[c];
  acc += a.x*lW[c]  + a.y*lW[256+c]  + a.z*lW[512+c]  + a.w*lW[768+c];
  acc += xv.x*rW[c] + xv.y*rW[256+c] + xv.z*rW[512+c] + xv.w*rW[768+c];
  out[(size_t)blockIdx.x*256 + c] = fmaxf(acc, 0.f);
}

// ---------------- generic f32 GEMM, 128x128 tile, 8x8 microtile ----------------
#define GF_BIAS    1
#define GF_RELU    2
#define GF_RESID   4
#define GF_RESID_B 8
#define GF_ADDC    32
#define GF_ATOMIC  64

template<int FLAGS>
__global__ __launch_bounds__(256) void k_gemm(const float* __restrict__ A, const float* __restrict__ Bm,
                       const float* __restrict__ bias, const float* __restrict__ resid,
                       float* __restrict__ C, int M, int Nn, int K){
  __shared__ float As[16][128];
  __shared__ float Bs[16][128];
  const int m0 = blockIdx.x*128, n0 = blockIdx.y*128;
  const int kChunk = K / gridDim.z;
  const int kBeg = blockIdx.z * kChunk;
  const int tid = threadIdx.x;
  const int tm = tid>>4, tn = tid&15;
  const int mA = tid>>2, kA = (tid&3)*4;
  const int kB = tid>>4, nB = (tid&15)*8;
  float acc[8][8] = {};
  for (int k0=kBeg; k0<kBeg+kChunk; k0+=16){
    float4 a0 = *reinterpret_cast<const float4*>(A + (size_t)(m0+mA)*K + k0 + kA);
    float4 a1 = *reinterpret_cast<const float4*>(A + (size_t)(m0+mA+64)*K + k0 + kA);
    float4 b0 = *reinterpret_cast<const float4*>(Bm + (size_t)(k0+kB)*Nn + n0 + nB);
    float4 b1 = *reinterpret_cast<const float4*>(Bm + (size_t)(k0+kB)*Nn + n0 + nB + 4);
    __syncthreads();    // previous tile consumed
    As[kA+0][mA]=a0.x; As[kA+1][mA]=a0.y; As[kA+2][mA]=a0.z; As[kA+3][mA]=a0.w;
    As[kA+0][mA+64]=a1.x; As[kA+1][mA+64]=a1.y; As[kA+2][mA+64]=a1.z; As[kA+3][mA+64]=a1.w;
    *reinterpret_cast<float4*>(&Bs[kB][nB])   = b0;
    *reinterpret_cast<float4*>(&Bs[kB][nB+4]) = b1;
    __syncthreads();    // tile ready
    #pragma unroll
    for (int kk=0;kk<16;++kk){
      float4 x0 = *reinterpret_cast<const float4*>(&As[kk][tm*8]);
      float4 x1 = *reinterpret_cast<const float4*>(&As[kk][tm*8+4]);
      float4 y0 = *reinterpret_cast<const float4*>(&Bs[kk][tn*8]);
      float4 y1 = *reinterpret_cast<const float4*>(&Bs[kk][tn*8+4]);
      float av[8]={x0.x,x0.y,x0.z,x0.w,x1.x,x1.y,x1.z,x1.w};
      float bv[8]={y0.x,y0.y,y0.z,y0.w,y1.x,y1.y,y1.z,y1.w};
      #pragma unroll
      for (int i=0;i<8;++i){
        #pragma unroll
        for (int j=0;j<8;++j) acc[i][j] += av[i]*bv[j];
      }
    }
  }
  #pragma unroll
  for (int i=0;i<8;++i){
    const size_t m = (size_t)m0 + tm*8 + i;
    #pragma unroll
    for (int j=0;j<8;++j){
      const int n = n0 + tn*8 + j;
      size_t idx = m*(size_t)Nn + n;
      float v = acc[i][j];
      if (FLAGS & GF_ATOMIC){ atomicAdd(&C[idx], v); }
      else {
        if (FLAGS & GF_BIAS)    v += bias[n];
        if (FLAGS & GF_ADDC)    v += C[idx];
        if (FLAGS & GF_RELU)    v = fmaxf(v, 0.f);
        if (FLAGS & GF_RESID)   v += resid[idx];
        if (FLAGS & GF_RESID_B) v += resid[n];
        C[idx] = v;
      }
    }
  }
}

// ---------------- small utilities ----------------
__global__ void k_rowbias(const float* __restrict__ bias, float* __restrict__ C, int Nn, int total){
  int i = blockIdx.x*256 + threadIdx.x;
  if (i < total) C[i] = bias[i % Nn];
}
__global__ void k_transpose768(const float* __restrict__ in, float* __restrict__ outp){
  int idx = blockIdx.x*256 + threadIdx.x;    // 768*256 elements
  if (idx >= 768*256) return;
  int j = idx >> 8, k = idx & 255;
  outp[k*768 + j] = in[idx];
}
__global__ void k_qvec(const float* __restrict__ seed, const float* __restrict__ Wq,
                       const float* __restrict__ bq, float* __restrict__ qv){
  __shared__ float s[256];
  int t = threadIdx.x;
  s[t] = seed[t]; __syncthreads();
  float acc = bq[t];
  for (int c = 0; c < 256; ++c) acc += s[c] * Wq[c*256 + t];
  qv[t] = acc;
}
__global__ void k_concat(const float* __restrict__ p1, const float* __restrict__ p2,
                         const float* __restrict__ p3, float* __restrict__ pooled){
  int idx = blockIdx.x*256 + threadIdx.x;    // 256*768
  int b = idx / 768, j = idx % 768;
  float v = (j < 256) ? p1[b*256+j] : (j < 512) ? p2[b*256+j-256] : p3[b*256+j-512];
  pooled[idx] = v;
}

// ---------------- GRU: 2 graphs per block, gi computed on the fly ----------------
__global__ __launch_bounds__(256) void k_gru(const float* __restrict__ X, const float* __restrict__ WihT,
                      const float* __restrict__ WhhT, const float* __restrict__ gbih,
                      const float* __restrict__ gbhh, float* __restrict__ p2){
  const int b0 = blockIdx.x*2;
  const int c = threadIdx.x;
  __shared__ float hs0[256], hs1[256], xs0[256], xs1[256];
  hs0[c]=0.f; hs1[c]=0.f;
  const float bir=gbih[c], biz=gbih[256+c], bin=gbih[512+c];
  const float bhr=gbhh[c], bhz=gbhh[256+c], bhn=gbhh[512+c];
  for (int t=0; t<512; ++t){
    xs0[c] = X[((size_t)(b0*512 + t))*256 + c];
    xs1[c] = X[((size_t)((b0+1)*512 + t))*256 + c];
    __syncthreads();                                  // xs ready, hs from prev visible
    float ir0=0,iz0=0,in0=0, hr0=0,hz0=0,hn0=0;
    float ir1=0,iz1=0,in1=0, hr1=0,hz1=0,hn1=0;
    #pragma unroll 2
    for (int k=0;k<256;++k){
      float wir=WihT[k*768+c],     wiz=WihT[k*768+256+c], win=WihT[k*768+512+c];
      float whr=WhhT[k*768+c],     whz=WhhT[k*768+256+c], whn=WhhT[k*768+512+c];
      float x0=xs0[k], x1=xs1[k], h0v=hs0[k], h1v=hs1[k];
      ir0+=x0*wir; iz0+=x0*wiz; in0+=x0*win;
      hr0+=h0v*whr; hz0+=h0v*whz; hn0+=h0v*whn;
      ir1+=x1*wir; iz1+=x1*wiz; in1+=x1*win;
      hr1+=h1v*whr; hz1+=h1v*whz; hn1+=h1v*whn;
    }
    float r0 = sigm(ir0+bir + hr0+bhr);
    float z0 = sigm(iz0+biz + hz0+bhz);
    float n0 = tanhf(in0+bin + r0*(hn0+bhn));
    float r1 = sigm(ir1+bir + hr1+bhr);
    float z1 = sigm(iz1+biz + hz1+bhz);
    float n1 = tanhf(in1+bin + r1*(hn1+bhn));
    float hv0 = (1.f-z0)*n0 + z0*hs0[c];
    float hv1 = (1.f-z1)*n1 + z1*hs1[c];
    __syncthreads();                                  // all reads done
    hs0[c]=hv0; hs1[c]=hv1;
  }
  __syncthreads();
  p2[(size_t)b0*256 + c]     = hs0[c];
  p2[(size_t)(b0+1)*256 + c] = hs1[c];
}

// ---------------- fused SAB attention: per (graph-in-chunk, 8 q-rows) ----------------
__global__ __launch_bounds__(256) void k_attn(float* __restrict__ Q, const float* __restrict__ K,
                       const float* __restrict__ V){
  __shared__ float  Qs[8*256];       // 8KB
  __shared__ float  S [8*512];       // 16KB
  __shared__ float4 Ks[32*64];       // 32KB (xor-swizzled)
  const int g = blockIdx.y, q0 = blockIdx.x*8, tid = threadIdx.x;
  const size_t gb = (size_t)g*512*256;
  for (int i=tid;i<2048;i+=256) Qs[i] = Q[gb + (size_t)q0*256 + i];
  const int q = tid>>5, kl = tid&31;
  const float4* qp = reinterpret_cast<const float4*>(Qs + q*256);
  float* Sq = S + q*512;
  for (int kt=0; kt<512; kt+=32){
    __syncthreads();
    for (int i=tid;i<2048;i+=256){
      int row = i>>6, c4 = i&63;
      Ks[row*64 + (c4^row)] = *reinterpret_cast<const float4*>(K + gb + (size_t)(kt+row)*256 + c4*4);
    }
    __syncthreads();
    float d = 0.f;
    #pragma unroll
    for (int c4=0;c4<64;++c4){
      float4 qa = qp[c4];
      float4 ka = Ks[kl*64 + (c4^kl)];
      d += qa.x*ka.x + qa.y*ka.y + qa.z*ka.z + qa.w*ka.w;
    }
    Sq[kt+kl] = d;
  }
  __syncthreads();
  // softmax over the 512 raw dots of row q (scale 1/sqrt(256)=1/16)
  float m = -3e38f;
  for (int j=kl;j<512;j+=32) m = fmaxf(m, Sq[j]);
  #pragma unroll
  for (int o=1;o<32;o<<=1) m = fmaxf(m, __shfl_xor(m,o));
  float sum = 0.f;
  for (int j=kl;j<512;j+=32){ float e = __expf((Sq[j]-m)*0.0625f); Sq[j]=e; sum+=e; }
  #pragma unroll
  for (int o=1;o<32;o<<=1) sum += __shfl_xor(sum,o);
  const float inv = 1.f/sum;
  __syncthreads();
  // AV: thread owns (q, 8 channels)
  const int c0 = kl*8;
  float a0=0,a1=0,a2=0,a3=0,a4=0,a5=0,a6=0,a7=0;
  for (int k=0;k<512;++k){
    float a = Sq[k];
    const float* vp = V + gb + (size_t)k*256 + c0;
    float4 v0 = *reinterpret_cast<const float4*>(vp);
    float4 v1 = *reinterpret_cast<const float4*>(vp+4);
    a0+=a*v0.x; a1+=a*v0.y; a2+=a*v0.z; a3+=a*v0.w;
    a4+=a*v1.x; a5+=a*v1.y; a6+=a*v1.z; a7+=a*v1.w;
  }
  float* op = Q + gb + (size_t)(q0+q)*256 + c0;   // overwrite own Q rows with AV
  float4 o0 = {a0*inv,a1*inv,a2*inv,a3*inv};
  float4 o1 = {a4*inv,a5*inv,a6*inv,a7*inv};
  *reinterpret_cast<float4*>(op)   = o0;
  *reinterpret_cast<float4*>(op+4) = o1;
}

// ---------------- PMA attention (1 query per graph), chunked ----------------
__global__ __launch_bounds__(256) void k_attn2(const float* __restrict__ K2, const float* __restrict__ V2,
                        const float* __restrict__ qv, float* __restrict__ av2){
  int g = blockIdx.x, tid = threadIdx.x;
  __shared__ float qs[256];
  __shared__ float sc[512];
  __shared__ float red[4];
  qs[tid] = qv[tid];
  __syncthreads();
  const size_t gb = (size_t)g*512*256;
  float l0=0.f, l1=0.f;
  for (int j0=0;j0<2;++j0){
    int j = tid + j0*256;
    const float* kr = K2 + gb + (size_t)j*256;
    float a = 0.f;
    for (int c=0;c<256;c+=4){
      float4 k4 = *reinterpret_cast<const float4*>(kr + c);
      a += k4.x*qs[c] + k4.y*qs[c+1] + k4.z*qs[c+2] + k4.w*qs[c+3];
    }
    a *= 0.0625f;
    if (j0) l1=a; else l0=a;
  }
  float m = fmaxf(l0,l1);
  #pragma unroll
  for (int o=1;o<64;o<<=1) m = fmaxf(m, __shfl_xor(m,o));
  if ((tid&63)==0) red[tid>>6] = m;
  __syncthreads();
  m = fmaxf(fmaxf(red[0],red[1]), fmaxf(red[2],red[3]));
  __syncthreads();
  float e0 = __expf(l0-m), e1 = __expf(l1-m);
  sc[tid]=e0; sc[tid+256]=e1;
  float s = e0+e1;
  #pragma unroll
  for (int o=1;o<64;o<<=1) s += __shfl_xor(s,o);
  if ((tid&63)==0) red[tid>>6] = s;
  __syncthreads();
  s = red[0]+red[1]+red[2]+red[3];
  float invs = 1.f/s;
  float acc = 0.f;
  for (int j=0;j<512;++j) acc += sc[j] * V2[gb + (size_t)j*256 + tid];
  av2[(size_t)g*256+tid] = acc*invs;
}

// =====================================================================
extern "C" void kernel_launch(void* const* d_in, const int* in_sizes, int n_in,
                              void* d_out, int out_size, void* d_ws, size_t ws_size,
                              hipStream_t stream){
  const int*   x      = (const int*)  d_in[0];
  const int*   ei     = (const int*)  d_in[1];
  const float* emb_w  = (const float*)d_in[3];
  const float* c1_lW  = (const float*)d_in[4];
  const float* c1_lb  = (const float*)d_in[5];
  const float* c1_rW  = (const float*)d_in[6];
  const float* t1     = (const float*)d_in[7];
  const float* c2_lW  = (const float*)d_in[8];
  const float* c2_lb  = (const float*)d_in[9];
  const float* c2_rW  = (const float*)d_in[10];
  const float* t2     = (const float*)d_in[11];
  const float* mlp_W  = (const float*)d_in[12];
  const float* mlp_b  = (const float*)d_in[13];
  const float* gWih   = (const float*)d_in[14];
  const float* gWhh   = (const float*)d_in[15];
  const float* gbih   = (const float*)d_in[16];
  const float* gbhh   = (const float*)d_in[17];
  const float* stWq   = (const float*)d_in[18];
  const float* stbq   = (const float*)d_in[19];
  const float* stWk   = (const float*)d_in[20];
  const float* stbk   = (const float*)d_in[21];
  const float* stWv   = (const float*)d_in[22];
  const float* stbv   = (const float*)d_in[23];
  const float* stWo   = (const float*)d_in[24];
  const float* stbo   = (const float*)d_in[25];
  const float* stlW   = (const float*)d_in[26];
  const float* stlb   = (const float*)d_in[27];
  const float* pma_lW = (const float*)d_in[28];
  const float* pma_lb = (const float*)d_in[29];
  const float* seed   = (const float*)d_in[30];
  const float* fin_W  = (const float*)d_in[31];
  const float* fin_b  = (const float*)d_in[32];
  float* out = (float*)d_out;

  // ---- workspace carve (peak ~196 MB) ----
  float* H2   = (float*)d_ws;                    // 33,554,432 (NN x 256, persists)
  float* bufA = H2   + (size_t)33554432;         // 4,194,304  (chunk buf)
  float* bufB = bufA + (size_t)4194304;
  float* bufC = bufB + (size_t)4194304;
  float* h0   = bufC + (size_t)4194304;          // NN*4
  float* ag1  = h0   + (size_t)524288;           // NN*4
  float* wT1  = ag1  + (size_t)524288;           // 256*768 WihT
  float* wT2  = wT1  + (size_t)196608;           // 256*768 WhhT
  float* p1   = wT2  + (size_t)196608;           // 256*256
  float* p2   = p1   + (size_t)65536;
  float* p3   = p2   + (size_t)65536;
  float* av2  = p3   + (size_t)65536;
  float* s1   = av2  + (size_t)65536;
  float* s2v  = s1   + (size_t)65536;
  float* v3   = s2v  + (size_t)65536;
  float* h3   = v3   + (size_t)65536;
  float* pooled = h3 + (size_t)65536;            // 256*768
  float* qv   = pooled + (size_t)196608;         // 256 (+pad)
  int*   deg  = (int*)(qv + 320);                // NN
  int*   offs = deg  + 131072;                   // NN + pad (offs[NN] used)
  int*   cur  = offs + 131200;                   // NN
  int*   esrc = cur  + 131072;                   // NE
  int*   bsum = esrc + 262144;                   // 128
  int*   boff = bsum + 128;                      // 128
  size_t need = ((size_t)((boff + 128) - (int*)d_ws))*4 + 4096;
  if (ws_size < need) return;   // diagnostic: clean absmax failure instead of OOB hang

  const int ls0 = 65536, ls1 = 256;              // set-transformer layer strides

  // ---- 1. node encoder ----
  k_node_enc<<<NN/256, 256, 0, stream>>>(x, emb_w, h0);

  // ---- 2. CSR ----
  k_zero<<<NN/256, 256, 0, stream>>>(deg, NN);
  k_count<<<NE/256, 256, 0, stream>>>(ei, deg);
  k_blocksum<<<128, 256, 0, stream>>>(deg, bsum);
  k_scanbsum<<<1, 128, 0, stream>>>(bsum, boff, offs + NN);
  k_scanchunk<<<128, 256, 0, stream>>>(deg, boff, offs);
  k_zero<<<NN/256, 256, 0, stream>>>(cur, NN);
  k_fill<<<NE/256, 256, 0, stream>>>(ei, offs, cur, esrc);

  // ---- 3. conv1 aggregation (full batch, tiny: NN x 4) ----
  k_aggr4<<<NN/256, 256, 0, stream>>>(h0, offs, esrc, t1, ag1);

  // ---- 4. conv1 + conv2, chunked over 32-graph groups ----
  for (int cg = 0; cg < NCHUNK; ++cg){
    const int base = cg * NCN;
    float* Hc = H2 + (size_t)base * 256;
    k_conv1_lin<<<NCN, 256, 0, stream>>>(ag1, h0, c1_lW, c1_lb, c1_rW, bufA, base);   // h1_c
    k_aggr256<<<NCN, 256, 0, stream>>>(bufA, offs, esrc, t2, bufB, base);             // ag2_c
    k_gemm<0><<<dim3(NCN/128, 2, 1), 256, 0, stream>>>(bufB, c2_lW, nullptr, nullptr, Hc, NCN, 256, 256);
    k_gemm<GF_BIAS|GF_ADDC|GF_RELU><<<dim3(NCN/128, 2, 1), 256, 0, stream>>>(bufA, c2_rW, c2_lb, nullptr, Hc, NCN, 256, 256);
  }
  // H2 = h2 (full)

  // ---- 5. p1 = MLP pool (M=256, K=131072, split-K atomic) ----
  k_rowbias<<<256, 256, 0, stream>>>(mlp_b, p1, 256, 65536);
  k_gemm<GF_ATOMIC><<<dim3(2, 2, 64), 256, 0, stream>>>(H2, mlp_W, nullptr, nullptr, p1, 256, 256, NN);

  // ---- 6. GRU (gi on the fly, no GI buffer) ----
  k_transpose768<<<768, 256, 0, stream>>>(gWih, wT1);
  k_transpose768<<<768, 256, 0, stream>>>(gWhh, wT2);
  k_gru<<<128, 256, 0, stream>>>(H2, wT1, wT2, gbih, gbhh, p2);

  // ---- 7. set transformer, chunked over 32-graph groups ----
  k_qvec<<<1, 256, 0, stream>>>(seed, stWq + ls0, stbq + ls1, qv);
  for (int cg = 0; cg < NCHUNK; ++cg){
    const int base = cg * NCN;
    float* Hc = H2 + (size_t)base * 256;
    const dim3 gg(NCN/128, 2, 1);
    k_gemm<GF_BIAS><<<gg, 256, 0, stream>>>(Hc, stWq, stbq, nullptr, bufA, NCN, 256, 256);  // Q
    k_gemm<GF_BIAS><<<gg, 256, 0, stream>>>(Hc, stWk, stbk, nullptr, bufB, NCN, 256, 256);  // K
    k_gemm<GF_BIAS><<<gg, 256, 0, stream>>>(Hc, stWv, stbv, nullptr, bufC, NCN, 256, 256);  // V
    k_attn<<<dim3(64, CH), 256, 0, stream>>>(bufA, bufB, bufC);                             // AV -> bufA
    k_gemm<GF_BIAS|GF_RESID><<<gg, 256, 0, stream>>>(bufA, stWo, stbo, Hc, Hc, NCN, 256, 256);       // h_sab (in-place over h2)
    k_gemm<GF_BIAS|GF_RELU|GF_RESID><<<gg, 256, 0, stream>>>(Hc, stlW, stlb, Hc, bufA, NCN, 256, 256); // h_enc
    k_gemm<GF_BIAS|GF_RELU><<<gg, 256, 0, stream>>>(bufA, pma_lW, pma_lb, nullptr, bufB, NCN, 256, 256); // kk
    k_gemm<GF_BIAS><<<gg, 256, 0, stream>>>(bufB, stWk + ls0, stbk + ls1, nullptr, bufA, NCN, 256, 256); // K2
    k_gemm<GF_BIAS><<<gg, 256, 0, stream>>>(bufB, stWv + ls0, stbv + ls1, nullptr, bufC, NCN, 256, 256); // V2
    k_attn2<<<CH, 256, 0, stream>>>(bufA, bufC, qv, av2 + (size_t)cg*CH*256);
  }

  // ---- 8. PMA tail + decoder SAB (small, full batch) ----
  k_gemm<GF_BIAS|GF_RESID_B><<<dim3(2, 2, 1), 256, 0, stream>>>(av2, stWo + ls0, stbo + ls1, seed, s1, 256, 256, 256);
  k_gemm<GF_BIAS|GF_RELU|GF_RESID><<<dim3(2, 2, 1), 256, 0, stream>>>(s1, stlW + ls0, stlb + ls1, s1, s2v, 256, 256, 256);
  k_gemm<GF_BIAS><<<dim3(2, 2, 1), 256, 0, stream>>>(s2v, stWv + 2*ls0, stbv + 2*ls1, nullptr, v3, 256, 256, 256);
  k_gemm<GF_BIAS|GF_RESID><<<dim3(2, 2, 1), 256, 0, stream>>>(v3, stWo + 2*ls0, stbo + 2*ls1, s2v, h3, 256, 256, 256);
  k_gemm<GF_BIAS|GF_RELU|GF_RESID><<<dim3(2, 2, 1), 256, 0, stream>>>(h3, stlW + 2*ls0, stlb + 2*ls1, h3, p3, 256, 256, 256);

  // ---- 9. concat + final linear ----
  k_concat<<<768, 256, 0, stream>>>(p1, p2, p3, pooled);
  k_gemm<GF_BIAS><<<dim3(2, 6, 1), 256, 0, stream>>>(pooled, fin_W, fin_b, nullptr, out, 256, 768, 768);
}

// Round 3
// 12280.616 us; speedup vs baseline: 1.6284x; 1.6284x over previous
//
#include <hip/hip_runtime.h>
#include <hip/hip_bf16.h>
#include <math.h>

// ---- problem constants ----
constexpr int NN   = 131072;   // total nodes (B*NPG)
constexpr int NE   = 262144;   // edges
constexpr int BG   = 256;      // graphs
constexpr int CH   = 32;       // graphs per chunk
constexpr int NCHUNK = BG/CH;  // 8
constexpr int NCN  = CH*512;   // nodes per chunk = 16384

__device__ inline float sigm(float x){ return 1.f/(1.f+__expf(-x)); }
__device__ inline float blo(unsigned u){ union{unsigned a;float f;}v; v.a=u<<16; return v.f; }
__device__ inline float bhi(unsigned u){ union{unsigned a;float f;}v; v.a=u&0xffff0000u; return v.f; }
__device__ inline unsigned short f2bu(float f){
  union{float f;unsigned u;}v; v.f=f;
  unsigned u = v.u + 0x7fffu + ((v.u>>16)&1u);
  return (unsigned short)(u>>16);
}

__global__ void k_zero(int* __restrict__ p, int n){
  int i = blockIdx.x*256 + threadIdx.x;
  if (i < n) p[i] = 0;
}

// ---------------- node encoder ----------------
__global__ void k_node_enc(const int* __restrict__ x, const float* __restrict__ emb,
                           float* __restrict__ h0){
  int n = blockIdx.x*256 + threadIdx.x;
  if (n >= NN) return;
  int nt = x[2*n], ninv = x[2*n+1];
  float4 v; v.x = emb[nt*3+0]; v.y = emb[nt*3+1]; v.z = emb[nt*3+2]; v.w = (float)ninv;
  reinterpret_cast<float4*>(h0)[n] = v;
}

// ---------------- CSR build (by dst) ----------------
__global__ void k_count(const int* __restrict__ ei, int* __restrict__ deg){
  int e = blockIdx.x*256 + threadIdx.x;
  if (e >= NE) return;
  atomicAdd(&deg[ei[NE + e]], 1);
}
__global__ void k_blocksum(const int* __restrict__ deg, int* __restrict__ bsum){
  __shared__ int sd[256];
  int t = threadIdx.x;
  const int* p = deg + blockIdx.x*1024;
  int s = p[t*4] + p[t*4+1] + p[t*4+2] + p[t*4+3];
  sd[t]=s; __syncthreads();
  for (int d=128; d>0; d>>=1){ if (t<d) sd[t]+=sd[t+d]; __syncthreads(); }
  if (!t) bsum[blockIdx.x] = sd[0];
}
__global__ void k_scanbsum(const int* __restrict__ bsum, int* __restrict__ boff, int* __restrict__ offN){
  __shared__ int s[128];
  int t = threadIdx.x;           // 128 threads
  int mine = bsum[t];
  s[t]=mine; __syncthreads();
  for (int d=1; d<128; d<<=1){ int v = (t>=d)? s[t-d]:0; __syncthreads(); s[t]+=v; __syncthreads(); }
  boff[t] = s[t]-mine;
  if (t==127) offN[0] = s[127];
}
__global__ void k_scanchunk(const int* __restrict__ deg, const int* __restrict__ boff, int* __restrict__ offs){
  __shared__ int ts[256];
  int t = threadIdx.x, b = blockIdx.x;
  const int* p = deg + b*1024;
  int v0=p[t*4],v1=p[t*4+1],v2=p[t*4+2],v3=p[t*4+3];
  int mysum=v0+v1+v2+v3;
  ts[t]=mysum; __syncthreads();
  for (int d=1; d<256; d<<=1){ int v=(t>=d)?ts[t-d]:0; __syncthreads(); ts[t]+=v; __syncthreads(); }
  int ex = ts[t]-mysum + boff[b];
  int* o = offs + b*1024 + t*4;
  o[0]=ex; o[1]=ex+v0; o[2]=ex+v0+v1; o[3]=ex+v0+v1+v2;
}
__global__ void k_fill(const int* __restrict__ ei, const int* __restrict__ offs,
                       int* __restrict__ cur, int* __restrict__ esrc){
  int e = blockIdx.x*256 + threadIdx.x;
  if (e >= NE) return;
  int dst = ei[NE+e];
  int pos = offs[dst] + atomicAdd(&cur[dst],1);
  esrc[pos] = ei[e];
}

// ---------------- softmax aggregation, 4-channel (conv1) ----------------
__global__ void k_aggr4(const float* __restrict__ h, const int* __restrict__ offs,
                        const int* __restrict__ esrc, const float* __restrict__ tptr,
                        float* __restrict__ ag){
  int n = blockIdx.x*256 + threadIdx.x;
  if (n >= NN) return;
  int s = offs[n], e = offs[n+1];
  float4 z = {0,0,0,0};
  if (s == e){ reinterpret_cast<float4*>(ag)[n] = z; return; }
  float t = *tptr;
  float4 m = {-3e38f,-3e38f,-3e38f,-3e38f};
  for (int i=s;i<e;++i){
    float4 v = reinterpret_cast<const float4*>(h)[esrc[i]];
    m.x=fmaxf(m.x,v.x*t); m.y=fmaxf(m.y,v.y*t); m.z=fmaxf(m.z,v.z*t); m.w=fmaxf(m.w,v.w*t);
  }
  float4 num=z, den=z;
  for (int i=s;i<e;++i){
    float4 v = reinterpret_cast<const float4*>(h)[esrc[i]];
    float ex;
    ex=__expf(v.x*t-m.x); num.x+=v.x*ex; den.x+=ex;
    ex=__expf(v.y*t-m.y); num.y+=v.y*ex; den.y+=ex;
    ex=__expf(v.z*t-m.z); num.z+=v.z*ex; den.z+=ex;
    ex=__expf(v.w*t-m.w); num.w+=v.w*ex; den.w+=ex;
  }
  float4 r = {num.x/den.x, num.y/den.y, num.z/den.z, num.w/den.w};
  reinterpret_cast<float4*>(ag)[n] = r;
}

// ---------------- softmax aggregation, 256-channel, chunked ----------------
__global__ __launch_bounds__(256) void k_aggr256(const float* __restrict__ hloc, const int* __restrict__ offs,
                          const int* __restrict__ esrc, const float* __restrict__ tptr,
                          float* __restrict__ ag, int base){
  int n = base + blockIdx.x, c = threadIdx.x;
  int s = offs[n], e = offs[n+1];
  if (s == e){ ag[(size_t)blockIdx.x*256+c] = 0.f; return; }
  float t = *tptr;
  float m = -3e38f;
  for (int i=s;i<e;++i) m = fmaxf(m, hloc[(size_t)(esrc[i]-base)*256 + c]*t);
  float num=0.f, den=0.f;
  for (int i=s;i<e;++i){
    float v = hloc[(size_t)(esrc[i]-base)*256 + c];
    float ex = __expf(v*t - m);
    num += v*ex; den += ex;
  }
  ag[(size_t)blockIdx.x*256+c] = num/den;
}

// ---------------- conv1 linear (K=4, fused), chunked ----------------
__global__ __launch_bounds__(256) void k_conv1_lin(const float* __restrict__ ag, const float* __restrict__ h0,
                            const float* __restrict__ lW, const float* __restrict__ lb,
                            const float* __restrict__ rW, float* __restrict__ out, int base){
  int n = base + blockIdx.x, c = threadIdx.x;
  float4 a  = reinterpret_cast<const float4*>(ag)[n];
  float4 xv = reinterpret_cast<const float4*>(h0)[n];
  float acc = lb[c];
  acc += a.x*lW[c]  + a.y*lW[256+c]  + a.z*lW[512+c]  + a.w*lW[768+c];
  acc += xv.x*rW[c] + xv.y*rW[256+c] + xv.z*rW[512+c] + xv.w*rW[768+c];
  out[(size_t)blockIdx.x*256 + c] = fmaxf(acc, 0.f);
}

// ---------------- generic f32 GEMM, 128x128 tile, 8x8 microtile ----------------
#define GF_BIAS    1
#define GF_RELU    2
#define GF_RESID   4
#define GF_RESID_B 8
#define GF_ADDC    32
#define GF_ATOMIC  64
#define GF_BF16    128

template<int FLAGS>
__global__ __launch_bounds__(256) void k_gemm(const float* __restrict__ A, const float* __restrict__ Bm,
                       const float* __restrict__ bias, const float* __restrict__ resid,
                       float* __restrict__ C, int M, int Nn, int K){
  __shared__ float As[16][128];
  __shared__ float Bs[16][128];
  const int m0 = blockIdx.x*128, n0 = blockIdx.y*128;
  const int kChunk = K / gridDim.z;
  const int kBeg = blockIdx.z * kChunk;
  const int tid = threadIdx.x;
  const int tm = tid>>4, tn = tid&15;
  const int mA = tid>>2, kA = (tid&3)*4;
  const int kB = tid>>4, nB = (tid&15)*8;
  float acc[8][8] = {};
  for (int k0=kBeg; k0<kBeg+kChunk; k0+=16){
    float4 a0 = *reinterpret_cast<const float4*>(A + (size_t)(m0+mA)*K + k0 + kA);
    float4 a1 = *reinterpret_cast<const float4*>(A + (size_t)(m0+mA+64)*K + k0 + kA);
    float4 b0 = *reinterpret_cast<const float4*>(Bm + (size_t)(k0+kB)*Nn + n0 + nB);
    float4 b1 = *reinterpret_cast<const float4*>(Bm + (size_t)(k0+kB)*Nn + n0 + nB + 4);
    __syncthreads();    // previous tile consumed
    As[kA+0][mA]=a0.x; As[kA+1][mA]=a0.y; As[kA+2][mA]=a0.z; As[kA+3][mA]=a0.w;
    As[kA+0][mA+64]=a1.x; As[kA+1][mA+64]=a1.y; As[kA+2][mA+64]=a1.z; As[kA+3][mA+64]=a1.w;
    *reinterpret_cast<float4*>(&Bs[kB][nB])   = b0;
    *reinterpret_cast<float4*>(&Bs[kB][nB+4]) = b1;
    __syncthreads();    // tile ready
    #pragma unroll
    for (int kk=0;kk<16;++kk){
      float4 x0 = *reinterpret_cast<const float4*>(&As[kk][tm*8]);
      float4 x1 = *reinterpret_cast<const float4*>(&As[kk][tm*8+4]);
      float4 y0 = *reinterpret_cast<const float4*>(&Bs[kk][tn*8]);
      float4 y1 = *reinterpret_cast<const float4*>(&Bs[kk][tn*8+4]);
      float av[8]={x0.x,x0.y,x0.z,x0.w,x1.x,x1.y,x1.z,x1.w};
      float bv[8]={y0.x,y0.y,y0.z,y0.w,y1.x,y1.y,y1.z,y1.w};
      #pragma unroll
      for (int i=0;i<8;++i){
        #pragma unroll
        for (int j=0;j<8;++j) acc[i][j] += av[i]*bv[j];
      }
    }
  }
  #pragma unroll
  for (int i=0;i<8;++i){
    const size_t m = (size_t)m0 + tm*8 + i;
    #pragma unroll
    for (int j=0;j<8;++j){
      const int n = n0 + tn*8 + j;
      size_t idx = m*(size_t)Nn + n;
      float v = acc[i][j];
      if (FLAGS & GF_ATOMIC){ atomicAdd(&C[idx], v); }
      else {
        if (FLAGS & GF_BIAS)    v += bias[n];
        if (FLAGS & GF_ADDC)    v += C[idx];
        if (FLAGS & GF_RELU)    v = fmaxf(v, 0.f);
        if (FLAGS & GF_RESID)   v += resid[idx];
        if (FLAGS & GF_RESID_B) v += resid[n];
        if (FLAGS & GF_BF16) reinterpret_cast<__hip_bfloat16*>(C)[idx] = __float2bfloat16(v);
        else C[idx] = v;
      }
    }
  }
}

// ---------------- small utilities ----------------
__global__ void k_rowbias(const float* __restrict__ bias, float* __restrict__ C, int Nn, int total){
  int i = blockIdx.x*256 + threadIdx.x;
  if (i < total) C[i] = bias[i % Nn];
}
// pack Wih/Whh (both [768][256] row-major) into WC[k][j] = {hi: bf16(Whh[j][k]), lo: bf16(Wih[j][k])}
__global__ void k_packw(const float* __restrict__ gWih, const float* __restrict__ gWhh,
                        unsigned* __restrict__ WC){
  int idx = blockIdx.x*256 + threadIdx.x;     // 768*256
  if (idx >= 196608) return;
  int j = idx >> 8, k = idx & 255;
  unsigned wi = f2bu(gWih[j*256 + k]);
  unsigned wh = f2bu(gWhh[j*256 + k]);
  WC[k*768 + j] = (wh<<16) | wi;
}
__global__ void k_qvec(const float* __restrict__ seed, const float* __restrict__ Wq,
                       const float* __restrict__ bq, float* __restrict__ qv){
  __shared__ float s[256];
  int t = threadIdx.x;
  s[t] = seed[t]; __syncthreads();
  float acc = bq[t];
  for (int c = 0; c < 256; ++c) acc += s[c] * Wq[c*256 + t];
  qv[t] = acc;
}
__global__ void k_concat(const float* __restrict__ p1, const float* __restrict__ p2,
                         const float* __restrict__ p3, float* __restrict__ pooled){
  int idx = blockIdx.x*256 + threadIdx.x;    // 256*768
  int b = idx / 768, j = idx % 768;
  float v = (j < 256) ? p1[b*256+j] : (j < 512) ? p2[b*256+j-256] : p3[b*256+j-512];
  pooled[idx] = v;
}

// ---------------- GRU v3: 1 graph/block (256 blocks), packed bf16 dual weights ----
// thread c owns channels (c, 256+c, 512+c) of both gi and gh -> gates in-thread.
__global__ __launch_bounds__(256) void k_gru3(const float* __restrict__ X, const unsigned* __restrict__ WC,
                      const float* __restrict__ gbih, const float* __restrict__ gbhh,
                      float* __restrict__ p2){
  const int g = blockIdx.x;
  const int c = threadIdx.x;
  __shared__ float2 XH[256];                      // (x_t[k], h_{t-1}[k])
  const float bir=gbih[c], biz=gbih[256+c], bin=gbih[512+c];
  const float bhr=gbhh[c], bhz=gbhh[256+c], bhn=gbhh[512+c];
  XH[c] = make_float2(X[((size_t)g*512)*256 + c], 0.f);
  const unsigned* w0 = WC + c;
  const unsigned* w1 = WC + 256 + c;
  const unsigned* w2 = WC + 512 + c;
  for (int t=0; t<512; ++t){
    __syncthreads();                              // XH ready
    float ir=0,iz=0,inn=0,hr=0,hz=0,hn=0;
    #pragma unroll 8
    for (int k=0;k<256;++k){
      float2 xh = XH[k];
      unsigned a = w0[(size_t)k*768];
      unsigned b = w1[(size_t)k*768];
      unsigned d = w2[(size_t)k*768];
      ir += xh.x*blo(a); hr += xh.y*bhi(a);
      iz += xh.x*blo(b); hz += xh.y*bhi(b);
      inn+= xh.x*blo(d); hn += xh.y*bhi(d);
    }
    float r = sigm(ir+bir + hr+bhr);
    float z = sigm(iz+biz + hz+bhz);
    float n = tanhf(inn+bin + r*(hn+bhn));
    float hold = XH[c].y;
    float hnew = (1.f-z)*n + z*hold;
    float xn = (t<511) ? X[((size_t)g*512 + t+1)*256 + c] : 0.f;
    __syncthreads();                              // all reads of XH done
    XH[c] = make_float2(xn, hnew);
  }
  __syncthreads();
  p2[(size_t)g*256 + c] = XH[c].y;
}

// ---------------- fused SAB attention, bf16 K/V: per (graph-in-chunk, 8 q-rows) ----
__global__ __launch_bounds__(256) void k_attn(float* __restrict__ Q, const __hip_bfloat16* __restrict__ K,
                       const __hip_bfloat16* __restrict__ V){
  __shared__ float Qs[8*256];        // 8KB
  __shared__ float S [8*512];        // 16KB
  __shared__ uint4 Ks[32*32];        // 16KB (xor-swizzled, 8 bf16 per uint4)
  const int g = blockIdx.y, q0 = blockIdx.x*8, tid = threadIdx.x;
  const size_t gb = (size_t)g*512*256;
  for (int i=tid;i<2048;i+=256) Qs[i] = Q[gb + (size_t)q0*256 + i];
  const int q = tid>>5, kl = tid&31;
  const float* qp = Qs + q*256;
  float* Sq = S + q*512;
  for (int kt=0; kt<512; kt+=32){
    __syncthreads();
    for (int i=tid;i<1024;i+=256){
      int row = i>>5, c8 = i&31;
      Ks[row*32 + (c8^row)] =
        reinterpret_cast<const uint4*>(K + gb + (size_t)(kt+row)*256)[c8];
    }
    __syncthreads();
    float d = 0.f;
    #pragma unroll
    for (int c8=0;c8<32;++c8){
      uint4 kv = Ks[kl*32 + (c8^kl)];
      const float* qq = qp + c8*8;
      d += qq[0]*blo(kv.x) + qq[1]*bhi(kv.x) + qq[2]*blo(kv.y) + qq[3]*bhi(kv.y)
         + qq[4]*blo(kv.z) + qq[5]*bhi(kv.z) + qq[6]*blo(kv.w) + qq[7]*bhi(kv.w);
    }
    Sq[kt+kl] = d;
  }
  __syncthreads();
  // softmax over 512 raw dots of row q (scale 1/16)
  float m = -3e38f;
  for (int j=kl;j<512;j+=32) m = fmaxf(m, Sq[j]);
  #pragma unroll
  for (int o=1;o<32;o<<=1) m = fmaxf(m, __shfl_xor(m,o));
  float sum = 0.f;
  for (int j=kl;j<512;j+=32){ float e = __expf((Sq[j]-m)*0.0625f); Sq[j]=e; sum+=e; }
  #pragma unroll
  for (int o=1;o<32;o<<=1) sum += __shfl_xor(sum,o);
  const float inv = 1.f/sum;
  __syncthreads();
  // AV: thread owns (q, 8 channels)
  const int c0 = kl*8;
  float a0=0,a1=0,a2=0,a3=0,a4=0,a5=0,a6=0,a7=0;
  for (int k=0;k<512;++k){
    float a = Sq[k];
    uint4 vv = *reinterpret_cast<const uint4*>(V + gb + (size_t)k*256 + c0);
    a0+=a*blo(vv.x); a1+=a*bhi(vv.x); a2+=a*blo(vv.y); a3+=a*bhi(vv.y);
    a4+=a*blo(vv.z); a5+=a*bhi(vv.z); a6+=a*blo(vv.w); a7+=a*bhi(vv.w);
  }
  float* op = Q + gb + (size_t)(q0+q)*256 + c0;   // overwrite own Q rows with AV
  float4 o0 = {a0*inv,a1*inv,a2*inv,a3*inv};
  float4 o1 = {a4*inv,a5*inv,a6*inv,a7*inv};
  *reinterpret_cast<float4*>(op)   = o0;
  *reinterpret_cast<float4*>(op+4) = o1;
}

// ---------------- PMA attention (1 query per graph), chunked ----------------
__global__ __launch_bounds__(256) void k_attn2(const float* __restrict__ K2, const float* __restrict__ V2,
                        const float* __restrict__ qv, float* __restrict__ av2){
  int g = blockIdx.x, tid = threadIdx.x;
  __shared__ float qs[256];
  __shared__ float sc[512];
  __shared__ float red[4];
  qs[tid] = qv[tid];
  __syncthreads();
  const size_t gb = (size_t)g*512*256;
  float l0=0.f, l1=0.f;
  for (int j0=0;j0<2;++j0){
    int j = tid + j0*256;
    const float* kr = K2 + gb + (size_t)j*256;
    float a = 0.f;
    for (int c=0;c<256;c+=4){
      float4 k4 = *reinterpret_cast<const float4*>(kr + c);
      a += k4.x*qs[c] + k4.y*qs[c+1] + k4.z*qs[c+2] + k4.w*qs[c+3];
    }
    a *= 0.0625f;
    if (j0) l1=a; else l0=a;
  }
  float m = fmaxf(l0,l1);
  #pragma unroll
  for (int o=1;o<64;o<<=1) m = fmaxf(m, __shfl_xor(m,o));
  if ((tid&63)==0) red[tid>>6] = m;
  __syncthreads();
  m = fmaxf(fmaxf(red[0],red[1]), fmaxf(red[2],red[3]));
  __syncthreads();
  float e0 = __expf(l0-m), e1 = __expf(l1-m);
  sc[tid]=e0; sc[tid+256]=e1;
  float s = e0+e1;
  #pragma unroll
  for (int o=1;o<64;o<<=1) s += __shfl_xor(s,o);
  if ((tid&63)==0) red[tid>>6] = s;
  __syncthreads();
  s = red[0]+red[1]+red[2]+red[3];
  float invs = 1.f/s;
  float acc = 0.f;
  for (int j=0;j<512;++j) acc += sc[j] * V2[gb + (size_t)j*256 + tid];
  av2[(size_t)g*256+tid] = acc*invs;
}

// =====================================================================
extern "C" void kernel_launch(void* const* d_in, const int* in_sizes, int n_in,
                              void* d_out, int out_size, void* d_ws, size_t ws_size,
                              hipStream_t stream){
  const int*   x      = (const int*)  d_in[0];
  const int*   ei     = (const int*)  d_in[1];
  const float* emb_w  = (const float*)d_in[3];
  const float* c1_lW  = (const float*)d_in[4];
  const float* c1_lb  = (const float*)d_in[5];
  const float* c1_rW  = (const float*)d_in[6];
  const float* t1     = (const float*)d_in[7];
  const float* c2_lW  = (const float*)d_in[8];
  const float* c2_lb  = (const float*)d_in[9];
  const float* c2_rW  = (const float*)d_in[10];
  const float* t2     = (const float*)d_in[11];
  const float* mlp_W  = (const float*)d_in[12];
  const float* mlp_b  = (const float*)d_in[13];
  const float* gWih   = (const float*)d_in[14];
  const float* gWhh   = (const float*)d_in[15];
  const float* gbih   = (const float*)d_in[16];
  const float* gbhh   = (const float*)d_in[17];
  const float* stWq   = (const float*)d_in[18];
  const float* stbq   = (const float*)d_in[19];
  const float* stWk   = (const float*)d_in[20];
  const float* stbk   = (const float*)d_in[21];
  const float* stWv   = (const float*)d_in[22];
  const float* stbv   = (const float*)d_in[23];
  const float* stWo   = (const float*)d_in[24];
  const float* stbo   = (const float*)d_in[25];
  const float* stlW   = (const float*)d_in[26];
  const float* stlb   = (const float*)d_in[27];
  const float* pma_lW = (const float*)d_in[28];
  const float* pma_lb = (const float*)d_in[29];
  const float* seed   = (const float*)d_in[30];
  const float* fin_W  = (const float*)d_in[31];
  const float* fin_b  = (const float*)d_in[32];
  float* out = (float*)d_out;

  // ---- workspace carve (peak ~196 MB, identical layout to round 2) ----
  float* H2   = (float*)d_ws;                    // 33,554,432 (NN x 256, persists)
  float* bufA = H2   + (size_t)33554432;         // 4,194,304  (chunk buf)
  float* bufB = bufA + (size_t)4194304;
  float* bufC = bufB + (size_t)4194304;
  float* h0   = bufC + (size_t)4194304;          // NN*4
  float* ag1  = h0   + (size_t)524288;           // NN*4
  float* wT1  = ag1  + (size_t)524288;           // 256*768 (WC packed weights)
  float* wT2  = wT1  + (size_t)196608;           // (free)
  float* p1   = wT2  + (size_t)196608;           // 256*256
  float* p2   = p1   + (size_t)65536;
  float* p3   = p2   + (size_t)65536;
  float* av2  = p3   + (size_t)65536;
  float* s1   = av2  + (size_t)65536;
  float* s2v  = s1   + (size_t)65536;
  float* v3   = s2v  + (size_t)65536;
  float* h3   = v3   + (size_t)65536;
  float* pooled = h3 + (size_t)65536;            // 256*768
  float* qv   = pooled + (size_t)196608;         // 256 (+pad)
  int*   deg  = (int*)(qv + 320);                // NN
  int*   offs = deg  + 131072;                   // NN + pad (offs[NN] used)
  int*   cur  = offs + 131200;                   // NN
  int*   esrc = cur  + 131072;                   // NE
  int*   bsum = esrc + 262144;                   // 128
  int*   boff = bsum + 128;                      // 128
  size_t need = ((size_t)((boff + 128) - (int*)d_ws))*4 + 4096;
  if (ws_size < need) return;   // diagnostic: clean absmax failure instead of OOB hang

  const int ls0 = 65536, ls1 = 256;              // set-transformer layer strides

  // ---- 1. node encoder ----
  k_node_enc<<<NN/256, 256, 0, stream>>>(x, emb_w, h0);

  // ---- 2. CSR ----
  k_zero<<<NN/256, 256, 0, stream>>>(deg, NN);
  k_count<<<NE/256, 256, 0, stream>>>(ei, deg);
  k_blocksum<<<128, 256, 0, stream>>>(deg, bsum);
  k_scanbsum<<<1, 128, 0, stream>>>(bsum, boff, offs + NN);
  k_scanchunk<<<128, 256, 0, stream>>>(deg, boff, offs);
  k_zero<<<NN/256, 256, 0, stream>>>(cur, NN);
  k_fill<<<NE/256, 256, 0, stream>>>(ei, offs, cur, esrc);

  // ---- 3. conv1 aggregation (full batch, tiny: NN x 4) ----
  k_aggr4<<<NN/256, 256, 0, stream>>>(h0, offs, esrc, t1, ag1);

  // ---- 4. conv1 + conv2, chunked over 32-graph groups ----
  for (int cg = 0; cg < NCHUNK; ++cg){
    const int base = cg * NCN;
    float* Hc = H2 + (size_t)base * 256;
    k_conv1_lin<<<NCN, 256, 0, stream>>>(ag1, h0, c1_lW, c1_lb, c1_rW, bufA, base);   // h1_c
    k_aggr256<<<NCN, 256, 0, stream>>>(bufA, offs, esrc, t2, bufB, base);             // ag2_c
    k_gemm<0><<<dim3(NCN/128, 2, 1), 256, 0, stream>>>(bufB, c2_lW, nullptr, nullptr, Hc, NCN, 256, 256);
    k_gemm<GF_BIAS|GF_ADDC|GF_RELU><<<dim3(NCN/128, 2, 1), 256, 0, stream>>>(bufA, c2_rW, c2_lb, nullptr, Hc, NCN, 256, 256);
  }
  // H2 = h2 (full)

  // ---- 5. p1 = MLP pool (M=256, K=131072, split-K atomic) ----
  k_rowbias<<<256, 256, 0, stream>>>(mlp_b, p1, 256, 65536);
  k_gemm<GF_ATOMIC><<<dim3(2, 2, 64), 256, 0, stream>>>(H2, mlp_W, nullptr, nullptr, p1, 256, 256, NN);

  // ---- 6. GRU (packed bf16 dual weights, 1 graph/block) ----
  k_packw<<<768, 256, 0, stream>>>(gWih, gWhh, (unsigned*)wT1);
  k_gru3<<<BG, 256, 0, stream>>>(H2, (const unsigned*)wT1, gbih, gbhh, p2);

  // ---- 7. set transformer, chunked over 32-graph groups ----
  k_qvec<<<1, 256, 0, stream>>>(seed, stWq + ls0, stbq + ls1, qv);
  for (int cg = 0; cg < NCHUNK; ++cg){
    const int base = cg * NCN;
    float* Hc = H2 + (size_t)base * 256;
    const dim3 gg(NCN/128, 2, 1);
    k_gemm<GF_BIAS><<<gg, 256, 0, stream>>>(Hc, stWq, stbq, nullptr, bufA, NCN, 256, 256);           // Q (f32)
    k_gemm<GF_BIAS|GF_BF16><<<gg, 256, 0, stream>>>(Hc, stWk, stbk, nullptr, bufB, NCN, 256, 256);   // K (bf16)
    k_gemm<GF_BIAS|GF_BF16><<<gg, 256, 0, stream>>>(Hc, stWv, stbv, nullptr, bufC, NCN, 256, 256);   // V (bf16)
    k_attn<<<dim3(64, CH), 256, 0, stream>>>(bufA, (const __hip_bfloat16*)bufB, (const __hip_bfloat16*)bufC); // AV -> bufA
    k_gemm<GF_BIAS|GF_RESID><<<gg, 256, 0, stream>>>(bufA, stWo, stbo, Hc, Hc, NCN, 256, 256);       // h_sab (in-place over h2)
    k_gemm<GF_BIAS|GF_RELU|GF_RESID><<<gg, 256, 0, stream>>>(Hc, stlW, stlb, Hc, bufA, NCN, 256, 256); // h_enc
    k_gemm<GF_BIAS|GF_RELU><<<gg, 256, 0, stream>>>(bufA, pma_lW, pma_lb, nullptr, bufB, NCN, 256, 256); // kk
    k_gemm<GF_BIAS><<<gg, 256, 0, stream>>>(bufB, stWk + ls0, stbk + ls1, nullptr, bufA, NCN, 256, 256); // K2 (f32)
    k_gemm<GF_BIAS><<<gg, 256, 0, stream>>>(bufB, stWv + ls0, stbv + ls1, nullptr, bufC, NCN, 256, 256); // V2 (f32)
    k_attn2<<<CH, 256, 0, stream>>>(bufA, bufC, qv, av2 + (size_t)cg*CH*256);
  }

  // ---- 8. PMA tail + decoder SAB (small, full batch) ----
  k_gemm<GF_BIAS|GF_RESID_B><<<dim3(2, 2, 1), 256, 0, stream>>>(av2, stWo + ls0, stbo + ls1, seed, s1, 256, 256, 256);
  k_gemm<GF_BIAS|GF_RELU|GF_RESID><<<dim3(2, 2, 1), 256, 0, stream>>>(s1, stlW + ls0, stlb + ls1, s1, s2v, 256, 256, 256);
  k_gemm<GF_BIAS><<<dim3(2, 2, 1), 256, 0, stream>>>(s2v, stWv + 2*ls0, stbv + 2*ls1, nullptr, v3, 256, 256, 256);
  k_gemm<GF_BIAS|GF_RESID><<<dim3(2, 2, 1), 256, 0, stream>>>(v3, stWo + 2*ls0, stbo + 2*ls1, s2v, h3, 256, 256, 256);
  k_gemm<GF_BIAS|GF_RELU|GF_RESID><<<dim3(2, 2, 1), 256, 0, stream>>>(h3, stlW + 2*ls0, stlb + 2*ls1, h3, p3, 256, 256, 256);

  // ---- 9. concat + final linear ----
  k_concat<<<768, 256, 0, stream>>>(p1, p2, p3, pooled);
  k_gemm<GF_BIAS><<<dim3(2, 6, 1), 256, 0, stream>>>(pooled, fin_W, fin_b, nullptr, out, 256, 768, 768);
}